// Round 1
// 793.490 us; speedup vs baseline: 1.2073x; 1.2073x over previous
//
#include <hip/hip_runtime.h>
#include <cstdint>
#include <cstddef>

#define T_TASKS 32
#define S_SHOT  2048
#define F_FEAT  1024
#define C_CLS   512
#define MARGIN  0.1f
#define NBLK    (T_TASKS * (S_SHOT / 64))   // 1024 blocks, 1024 % 8 == 0

typedef _Float16 f16;
typedef _Float16 f16x4 __attribute__((ext_vector_type(4)));
typedef _Float16 f16x8 __attribute__((ext_vector_type(8)));
typedef float    f32x4 __attribute__((ext_vector_type(4)));

// async global->LDS, 16B per lane; LDS dest is wave-uniform base + lane*16
__device__ __forceinline__ void gl_lds16(const void* g, void* l) {
  auto gp = (const __attribute__((address_space(1))) uint32_t*)(g);
  auto lp = (__attribute__((address_space(3))) uint32_t*)(l);
  __builtin_amdgcn_global_load_lds(gp, lp, 16, 0, 0);
}

__device__ __forceinline__ void upd3(float v, int i,
                                     float& v1, int& i1,
                                     float& v2, int& i2,
                                     float& v3, int& i3) {
  if (v > v1 || (v == v1 && i < i1)) { v3=v2; i3=i2; v2=v1; i2=i1; v1=v; i1=i; }
  else if (v > v2 || (v == v2 && i < i2)) { v3=v2; i3=i2; v2=v; i2=i; }
  else if (v > v3 || (v == v3 && i < i3)) { v3=v; i3=i; }
}

// ---------------------------------------------------------------------------
// Pre-pass: W fp32 -> Wh (f16 hi part) in k-tiled + bank-swizzled layout,
// and wsq[t,c] = 0.5*sum(w^2).  UNCHANGED from previous version (isolating
// the gemm_argmax delta this round).
// ---------------------------------------------------------------------------
__global__ __launch_bounds__(256) void prep_w(const float* __restrict__ W,
                                              f16* __restrict__ Wh,
                                              float* __restrict__ wsq) {
  int rid = blockIdx.x * 4 + (threadIdx.x >> 6);  // (t,c) row, one wave each
  int ln  = threadIdx.x & 63;
  int c   = rid & (C_CLS - 1);
  int t   = rid >> 9;
  const float* wr = W + (size_t)rid * F_FEAT;
  double s = 0.0;
#pragma unroll
  for (int j = 0; j < 4; ++j) {
    int f = (j * 64 + ln) * 4;
    float4 v = *(const float4*)(wr + f);
    s += (double)v.x * v.x + (double)v.y * v.y +
         (double)v.z * v.z + (double)v.w * v.w;
    f16x4 h;
    h.x = (f16)v.x; h.y = (f16)v.y; h.z = (f16)v.z; h.w = (f16)v.w;
    int kt = f >> 5;
    int q  = (f >> 3) & 3;
    int jj = f & 7;                       // 0 or 4
    int u  = c * 4 + ((q + (c >> 1)) & 3);
    size_t off = ((size_t)(t * 32 + kt) << 14) + (size_t)u * 8 + jj;
    *(f16x4*)(Wh + off) = h;
  }
#pragma unroll
  for (int off = 32; off > 0; off >>= 1) s += __shfl_xor(s, off);
  if (ln == 0) wsq[rid] = (float)(0.5 * s);
}

// ---------------------------------------------------------------------------
// Main kernel LDS: main-loop buffers union'd with epilogue scratch.
// MainSh = 75776 B -> 2 blocks/CU (160 KiB pool).
// ---------------------------------------------------------------------------
struct MainSh {
  f16 W0[16384];        // 32 KB   W tile buffer A (512c x 32k, swizzled units)
  f16 W1[16384];        // 32 KB   W tile buffer B
  f16 Xh[64 * 40];      // 5120 B  64r x 32k hi, stride 40 (pad)
  f16 Xl[64 * 40];      // 5120 B  lo
};
struct EpiSh {
  float  swsq[C_CLS];
  float  cv[64][2][3];
  int    ci[64][2][3];
  double rs[48];        // refinement scores: 8 rows x 6 candidates per chunk
  int    amb_cnt;
  int    amb_list[64];
};
union ShU { MainSh m; EpiSh e; };

__device__ __forceinline__ void issue_w8(const f16* Wht, f16* dst, int ktn,
                                         int wv, int ln) {
  const f16* g = Wht + ((size_t)ktn << 14) + wv * 4096 + ln * 8;
  f16* l = dst + wv * 4096;
#pragma unroll
  for (int i = 0; i < 8; ++i) gl_lds16(g + i * 512, l + i * 512);
}

__device__ __forceinline__ void cvt_write_x(float4 a, float4 b,
                                            f16* xwh, f16* xwl) {
  f16x4 h, l;
  h.x = (f16)a.x; l.x = (f16)(a.x - (float)h.x);
  h.y = (f16)a.y; l.y = (f16)(a.y - (float)h.y);
  h.z = (f16)a.z; l.z = (f16)(a.z - (float)h.z);
  h.w = (f16)a.w; l.w = (f16)(a.w - (float)h.w);
  *(f16x4*)(xwh) = h;
  *(f16x4*)(xwl) = l;
  h.x = (f16)b.x; l.x = (f16)(b.x - (float)h.x);
  h.y = (f16)b.y; l.y = (f16)(b.y - (float)h.y);
  h.z = (f16)b.z; l.z = (f16)(b.z - (float)h.z);
  h.w = (f16)b.w; l.w = (f16)(b.w - (float)h.w);
  *(f16x4*)(xwh + 32 * 40) = h;
  *(f16x4*)(xwl + 32 * 40) = l;
}

// ---------------------------------------------------------------------------
// Main: per block = (task, 64 rows) x all 512 classes.
// 2-phase double-buffered pipeline: W(k+1) staged via global_load_lds into
// the alternate LDS buffer and X(k+1) loaded to regs at the TOP of iteration
// k; cvt+ds_write of X happens AFTER the MFMA cluster; the only vmcnt(0)
// drain sits just before the end-of-iteration barrier, so both streams get
// the whole compute phase of latency hiding.
// ---------------------------------------------------------------------------
__global__ __launch_bounds__(256, 2) void gemm_argmax(
    const float* __restrict__ X, const float* __restrict__ W,
    const f16* __restrict__ Wh, const float* __restrict__ wsq,
    int* __restrict__ out) {
  __shared__ __align__(16) ShU sh;

  const int tid = threadIdx.x;
  const int wv  = tid >> 6, ln = tid & 63;
  const int rg  = wv >> 1, cg = wv & 1;          // row-group, col-group
  const int m   = ln & 15, q = ln >> 4;

  // XCD-contiguous chunks: each XCD gets 4 whole tasks -> Wh L2-resident.
  int bx = blockIdx.x;
  bx = (bx & 7) * (NBLK / 8) + (bx >> 3);
  const int t    = bx >> 5, rb = bx & 31;
  const int row0 = rb * 64;

  const float* Xblk = X + ((size_t)t * S_SHOT + row0) * F_FEAT;
  const f16*   Wht  = Wh + ((size_t)(t * 32) << 14);

  // X staging mapping: two slots per thread (rows sr and sr+32)
  const int sr = tid >> 3, sq = tid & 7;
  const float* xg0 = Xblk + (size_t)sr * F_FEAT + sq * 4;
  const float* xg1 = xg0 + (size_t)32 * F_FEAT;
  f16* xwh = sh.m.Xh + sr * 40 + sq * 4;
  f16* xwl = sh.m.Xl + sr * 40 + sq * 4;

  // per-lane MFMA fragment base addresses
  const f16* aph = sh.m.Xh + (rg * 32 + m) * 40 + q * 8;
  const f16* apl = sh.m.Xl + (rg * 32 + m) * 40 + q * 8;
  const int c0 = cg * 256 + m;
  const int u0 = c0 * 4 + ((q + (c0 >> 1)) & 3); // swizzle is ct-invariant

  const f32x4 zero4 = {0.f, 0.f, 0.f, 0.f};
  f32x4 acc[2][16];
#pragma unroll
  for (int a = 0; a < 2; ++a)
#pragma unroll
    for (int b = 0; b < 16; ++b) acc[a][b] = zero4;

  f16* Wr = sh.m.W0;   // buffer being read this iteration
  f16* Ws = sh.m.W1;   // buffer being staged for next iteration

  // ---- prologue: stage tile 0 (full drain once)
  {
    float4 a = *(const float4*)(xg0);
    float4 b = *(const float4*)(xg1);
    issue_w8(Wht, Wr, 0, wv, ln);
    cvt_write_x(a, b, xwh, xwl);
    asm volatile("s_waitcnt vmcnt(0)" ::: "memory");
    asm volatile("s_waitcnt lgkmcnt(0)" ::: "memory");
    __builtin_amdgcn_s_barrier();
  }

#pragma unroll 1
  for (int kt = 0; kt < 32; ++kt) {
    const bool more = (kt < 31);
    float4 a, b;
    if (more) {
      // issue next-tile loads FIRST (X to regs, W direct-to-LDS alt buffer)
      a = *(const float4*)(xg0 + (kt + 1) * 32);
      b = *(const float4*)(xg1 + (kt + 1) * 32);
      issue_w8(Wht, Ws, kt + 1, wv, ln);
    }
    // read this wave's A fragments before anyone may overwrite sX
    f16x8 ah0 = *(const f16x8*)(aph);
    f16x8 ah1 = *(const f16x8*)(aph + 16 * 40);
    f16x8 al0 = *(const f16x8*)(apl);
    f16x8 al1 = *(const f16x8*)(apl + 16 * 40);
    asm volatile("s_waitcnt lgkmcnt(0)" ::: "memory");
    __builtin_amdgcn_s_barrier();

    __builtin_amdgcn_s_setprio(1);
    const f16* bp = Wr + u0 * 8;
#pragma unroll
    for (int ct = 0; ct < 16; ++ct) {
      f16x8 bh = *(const f16x8*)(bp + ct * 512);
      acc[0][ct] = __builtin_amdgcn_mfma_f32_16x16x32_f16(ah0, bh, acc[0][ct], 0, 0, 0);
      acc[0][ct] = __builtin_amdgcn_mfma_f32_16x16x32_f16(al0, bh, acc[0][ct], 0, 0, 0);
      acc[1][ct] = __builtin_amdgcn_mfma_f32_16x16x32_f16(ah1, bh, acc[1][ct], 0, 0, 0);
      acc[1][ct] = __builtin_amdgcn_mfma_f32_16x16x32_f16(al1, bh, acc[1][ct], 0, 0, 0);
    }
    __builtin_amdgcn_s_setprio(0);

    // write-late: convert X(kt+1) regs -> LDS after the MFMA cluster
    if (more) cvt_write_x(a, b, xwh, xwl);
    asm volatile("s_waitcnt vmcnt(0)" ::: "memory");
    asm volatile("s_waitcnt lgkmcnt(0)" ::: "memory");
    __builtin_amdgcn_s_barrier();
    f16* tmp = Wr; Wr = Ws; Ws = tmp;
  }
  __syncthreads();   // transition: main-loop LDS -> epilogue union

  // ---- epilogue setup (swsq load moved here; LDS aliases W buffers now)
  sh.e.swsq[tid]       = wsq[t * C_CLS + tid];
  sh.e.swsq[tid + 256] = wsq[t * C_CLS + tid + 256];
  if (tid == 0) sh.e.amb_cnt = 0;
  __syncthreads();

  // ---- top-3 per (row, col-half); C/D layout: col=lane&15, row=(lane>>4)*4+reg
#pragma unroll
  for (int rt = 0; rt < 2; ++rt) {
#pragma unroll
    for (int rr = 0; rr < 4; ++rr) {
      float v1 = -3.4e38f, v2 = -3.4e38f, v3 = -3.4e38f;
      int   i1 = 0x7fffffff, i2 = 0x7fffffff, i3 = 0x7fffffff;
#pragma unroll
      for (int ct = 0; ct < 16; ++ct) {
        int cidx = c0 + ct * 16;
        float sc = acc[rt][ct][rr] - sh.e.swsq[cidx];
        upd3(sc, cidx, v1, i1, v2, i2, v3, i3);
      }
      for (int off = 1; off < 16; off <<= 1) {
        float w1 = __shfl_xor(v1, off); int j1 = __shfl_xor(i1, off);
        float w2 = __shfl_xor(v2, off); int j2 = __shfl_xor(i2, off);
        float w3 = __shfl_xor(v3, off); int j3 = __shfl_xor(i3, off);
        upd3(w1, j1, v1, i1, v2, i2, v3, i3);
        upd3(w2, j2, v1, i1, v2, i2, v3, i3);
        upd3(w3, j3, v1, i1, v2, i2, v3, i3);
      }
      if (m == 0) {
        int row = rg * 32 + rt * 16 + q * 4 + rr;
        sh.e.cv[row][cg][0] = v1; sh.e.ci[row][cg][0] = i1;
        sh.e.cv[row][cg][1] = v2; sh.e.ci[row][cg][1] = i2;
        sh.e.cv[row][cg][2] = v3; sh.e.ci[row][cg][2] = i3;
      }
    }
  }
  __syncthreads();

  // ---- gate: write confident rows; queue ambiguous ones
  if (tid < 64) {
    float a1 = sh.e.cv[tid][0][0]; int aj = sh.e.ci[tid][0][0];
    float b1 = sh.e.cv[tid][1][0]; int bj = sh.e.ci[tid][1][0];
    float win, runner; int widx;
    if (a1 > b1 || (a1 == b1 && aj < bj)) {
      win = a1; widx = aj; runner = fmaxf(b1, sh.e.cv[tid][0][1]);
    } else {
      win = b1; widx = bj; runner = fmaxf(a1, sh.e.cv[tid][1][1]);
    }
    if (win - runner >= MARGIN) {
      out[t * S_SHOT + row0 + tid] = widx;
    } else {
      int p = atomicAdd(&sh.e.amb_cnt, 1);
      sh.e.amb_list[p] = tid;
    }
  }
  __syncthreads();

  // ---- fp64 refinement: one wave per (row,candidate), j-loop fully
  // unrolled so all 32 loads are in flight (kills the serial-latency tail).
  // Summation order and tie-break identical to previous version.
  int nA = sh.e.amb_cnt;
  for (int base = 0; base < nA; base += 8) {
    int nr = nA - base; if (nr > 8) nr = 8;
    int np = nr * 6;
    for (int p = wv; p < np; p += 4) {
      int rrow = p / 6;
      int cand = p - rrow * 6;
      int rl   = sh.e.amb_list[base + rrow];
      int g    = (cand >= 3) ? 1 : 0;
      int k    = cand - g * 3;
      int cidx = sh.e.ci[rl][g][k];
      const float* xr = X + ((size_t)t * S_SHOT + row0 + rl) * F_FEAT;
      const float* wr = W + ((size_t)t * C_CLS + cidx) * F_FEAT;
      double sd = 0.0, sw = 0.0;
#pragma unroll
      for (int j = 0; j < 16; ++j) {
        float xv  = xr[ln + 64 * j];
        float wv2 = wr[ln + 64 * j];
        sd += (double)xv * (double)wv2;
        sw += (double)wv2 * (double)wv2;
      }
#pragma unroll
      for (int off = 32; off > 0; off >>= 1) {
        sd += __shfl_xor(sd, off);
        sw += __shfl_xor(sw, off);
      }
      if (ln == 0) sh.e.rs[p] = sd - 0.5 * sw;
    }
    __syncthreads();
    if (tid < nr) {
      int rl = sh.e.amb_list[base + tid];
      double best = -1.0e300; int bidx = 0x7fffffff;
#pragma unroll
      for (int cand = 0; cand < 6; ++cand) {
        int g = cand / 3, k = cand % 3;
        int cidx = sh.e.ci[rl][g][k];
        double sc = sh.e.rs[tid * 6 + cand];
        if (sc > best || (sc == best && cidx < bidx)) { best = sc; bidx = cidx; }
      }
      out[t * S_SHOT + row0 + rl] = bidx;
    }
    __syncthreads();
  }
}

extern "C" void kernel_launch(void* const* d_in, const int* in_sizes, int n_in,
                              void* d_out, int out_size, void* d_ws, size_t ws_size,
                              hipStream_t stream) {
  (void)in_sizes; (void)n_in; (void)out_size;
  const float* X = (const float*)d_in[0];
  const float* W = (const float*)d_in[1];
  // temp (d_in[2]) is argmax-invariant; unused.
  const size_t wh_bytes = (size_t)T_TASKS * C_CLS * F_FEAT * sizeof(f16); // 33.5MB
  const size_t need = wh_bytes + (size_t)T_TASKS * C_CLS * sizeof(float);
  if (ws_size < need) return;  // fail loudly rather than corrupt memory
  f16*   Wh  = (f16*)d_ws;
  float* wsq = (float*)((char*)d_ws + wh_bytes);
  int*   out = (int*)d_out;
  prep_w<<<T_TASKS * C_CLS / 4, 256, 0, stream>>>(W, Wh, wsq);
  gemm_argmax<<<NBLK, 256, 0, stream>>>(X, W, Wh, wsq, out);
}